// Round 7
// baseline (47.516 us; speedup 1.0000x reference)
//
#include <hip/hip_runtime.h>
#include <hip/hip_bf16.h>

#define B_   4
#define C_   128
#define H_   64
#define W_   64
#define HW_  4096
#define KW_  7
#define PAD_ 3
#define G_   8
#define CPG_ 16

#define CPAD 136   // f16 elems per LDS row in proj; row stride 272 B

// attn LDS geometry
#define TS    16          // spatial tile
#define HALO  22          // TS + 6
#define NHP   (HALO*HALO) // 484 halo pixels
#define LP    24          // padded ushorts per pixel (48 B, 16B-aligned)

typedef _Float16 f16x8 __attribute__((ext_vector_type(8)));
typedef float    f32x4 __attribute__((ext_vector_type(4)));

static __device__ __forceinline__ unsigned short f2h(float f) {
    _Float16 h = (_Float16)f;
    union { _Float16 h; unsigned short u; } cv; cv.h = h;
    return cv.u;
}

// ---------------------------------------------------------------------------
// Kernel 0: convert Wq/Wk/Wv (f32) -> fp16 w16[3][128][128] in ws.
// 12288 float4 quads total; grid 48 x 256.
// ---------------------------------------------------------------------------
__global__ __launch_bounds__(256) void w16_kernel(
    const float* __restrict__ Wq,
    const float* __restrict__ Wk,
    const float* __restrict__ Wv,
    unsigned short* __restrict__ w16)
{
    const int gid = blockIdx.x * 256 + threadIdx.x;   // quad index
    const int m   = gid >> 12;                        // 4096 quads per matrix
    const int r   = gid & 4095;
    const float* src = (m == 0) ? Wq : ((m == 1) ? Wk : Wv);
    const float4 v = *(const float4*)(src + (size_t)r * 4);
    ushort4 hh;
    hh.x = f2h(v.x); hh.y = f2h(v.y); hh.z = f2h(v.z); hh.w = f2h(v.w);
    *(ushort4*)(w16 + ((size_t)m << 14) + (size_t)r * 4) = hh;
}

// ---------------------------------------------------------------------------
// Kernel A: fp16-MFMA 1x1 conv projections.
// A-fragments read directly from global fp16 W16 (L1-resident, 32 KB/matrix).
// Output: fp16, GROUP-PLANAR qkv16[m][b][g][pix][16] (pixel stride 32 B).
// grid: (64 p-tiles of 64 px, B, 3), block 256 (4 waves), LDS 17.4 KB.
// ---------------------------------------------------------------------------
__global__ __launch_bounds__(256) void proj_mfma(
    const float* __restrict__ x,
    const unsigned short* __restrict__ w16,
    unsigned short* __restrict__ qkv16)
{
    const int ptile = blockIdx.x;   // 0..63
    const int b     = blockIdx.y;
    const int m     = blockIdx.z;
    const unsigned short* wm = w16 + ((size_t)m << 14);
    const float* xb = x + (size_t)b * C_ * HW_;
    unsigned short* y = qkv16 + ((size_t)(m * B_ + b)) * HW_ * C_;
    const int p0  = ptile * 64;
    const int tid = threadIdx.x;

    __shared__ unsigned short xls[64 * CPAD];   // [p][c] f16 (transposed X)

    // stage X^T: 4c x 4p micro-transpose blocks (512 blocks, 2 iters)
    #pragma unroll
    for (int it = 0; it < 2; ++it) {
        const int idx = tid + it * 256;
        const int pq  = (idx & 15) * 4;
        const int cq  = (idx >> 4) * 4;
        const float* xp = xb + (size_t)cq * HW_ + p0 + pq;
        const float4 r0 = *(const float4*)(xp);
        const float4 r1 = *(const float4*)(xp + HW_);
        const float4 r2 = *(const float4*)(xp + 2 * HW_);
        const float4 r3 = *(const float4*)(xp + 3 * HW_);
        ushort4 hh;
        hh.x = f2h(r0.x); hh.y = f2h(r1.x); hh.z = f2h(r2.x); hh.w = f2h(r3.x);
        *(ushort4*)(&xls[(pq + 0) * CPAD + cq]) = hh;
        hh.x = f2h(r0.y); hh.y = f2h(r1.y); hh.z = f2h(r2.y); hh.w = f2h(r3.y);
        *(ushort4*)(&xls[(pq + 1) * CPAD + cq]) = hh;
        hh.x = f2h(r0.z); hh.y = f2h(r1.z); hh.z = f2h(r2.z); hh.w = f2h(r3.z);
        *(ushort4*)(&xls[(pq + 2) * CPAD + cq]) = hh;
        hh.x = f2h(r0.w); hh.y = f2h(r1.w); hh.z = f2h(r2.w); hh.w = f2h(r3.w);
        *(ushort4*)(&xls[(pq + 3) * CPAD + cq]) = hh;
    }
    __syncthreads();

    const int wv   = tid >> 6;     // wave id: owns 16 pixels
    const int lane = tid & 63;
    const int row  = lane & 15;
    const int kq   = lane >> 4;    // k-quad

    f32x4 acc[8];
    #pragma unroll
    for (int ot = 0; ot < 8; ++ot)
        acc[ot] = (f32x4){0.f, 0.f, 0.f, 0.f};

    #pragma unroll
    for (int ks = 0; ks < 4; ++ks) {
        const int cb = ks * 32 + kq * 8;
        // B-operand: pixels (free idx -> lane&15)
        const f16x8 bfrag = *(const f16x8*)(&xls[(wv * 16 + row) * CPAD + cb]);
        #pragma unroll
        for (int ot = 0; ot < 8; ++ot) {
            // A-operand: output channels, straight from global (L1)
            const f16x8 afrag = *(const f16x8*)(wm + (size_t)(ot * 16 + row) * C_ + cb);
            acc[ot] = __builtin_amdgcn_mfma_f32_16x16x32_f16(afrag, bfrag, acc[ot], 0, 0, 0);
        }
    }

    // D: lane holds D[o = ot*16 + kq*4 + reg][p = p0 + wv*16 + row]
    // group g == ot; within-group channel = kq*4 + reg.
    const int p = p0 + wv * 16 + row;
    #pragma unroll
    for (int ot = 0; ot < 8; ++ot) {
        ushort4 hh;
        hh.x = f2h(acc[ot][0]); hh.y = f2h(acc[ot][1]);
        hh.z = f2h(acc[ot][2]); hh.w = f2h(acc[ot][3]);
        *(ushort4*)(y + ((size_t)ot * HW_ + p) * CPG_ + kq * 4) = hh;
    }
}

// ---------------------------------------------------------------------------
// Kernel B: grouped 7x7 local attention, fp16 K/V halo staged in LDS.
// VERBATIM round-6 version (replay-proven).
// grid: (16 tiles, G, B), block 256 = one 16x16 tile, one group.
// ---------------------------------------------------------------------------
__global__ __launch_bounds__(256) void attn_kernel(
    const unsigned short* __restrict__ qkv16,
    const float* __restrict__ rel_h,   // [64][7]
    const float* __restrict__ rel_w,   // [64][7]
    float* __restrict__ out)           // [B][128][64][64]
{
    const int tile = blockIdx.x;
    const int g    = blockIdx.y;
    const int b    = blockIdx.z;
    const int h0   = (tile >> 2) * TS;
    const int w0   = (tile & 3) * TS;
    const int c0   = g * CPG_;

    __shared__ unsigned short kvls[2][NHP * LP];   // [k/v][pixel*24]

    const size_t gplane = (size_t)HW_ * CPG_;                 // per (b,g) plane
    const size_t mplane = (size_t)B_ * G_ * gplane;           // per matrix
    const unsigned short* qb = qkv16              + ((size_t)b * G_ + g) * gplane;
    const unsigned short* kb = qkv16 + mplane     + ((size_t)b * G_ + g) * gplane;
    const unsigned short* vb = qkv16 + 2 * mplane + ((size_t)b * G_ + g) * gplane;

    const int tid = threadIdx.x;

    // stage K and V halo: 1936 x 16B chunks, coalesced, zero-fill OOB
    #pragma unroll
    for (int it = 0; it < 8; ++it) {
        const int idx = tid + it * 256;
        if (idx < 2 * NHP * 2) {
            const int arr  = (idx >= NHP * 2) ? 1 : 0;
            const int r    = idx - arr * NHP * 2;
            const int lp   = r >> 1;
            const int half = r & 1;
            const int hy   = h0 + lp / HALO - PAD_;
            const int hx   = w0 + lp % HALO - PAD_;
            f16x8 val = (f16x8)(_Float16)0.f;
            if ((unsigned)hy < (unsigned)H_ && (unsigned)hx < (unsigned)W_) {
                const unsigned short* src = (arr ? vb : kb)
                    + (size_t)(hy * W_ + hx) * CPG_ + half * 8;
                val = *(const f16x8*)src;
            }
            *(f16x8*)(&kvls[arr][lp * LP + half * 8]) = val;
        }
    }
    __syncthreads();

    const int pw  = tid & 15;
    const int ph  = tid >> 4;
    const int pix = (h0 + ph) * W_ + (w0 + pw);

    // q fragment -> fp32
    float qv[CPG_];
    {
        const f16x8 q0 = *(const f16x8*)(qb + (size_t)pix * CPG_);
        const f16x8 q1 = *(const f16x8*)(qb + (size_t)pix * CPG_ + 8);
        #pragma unroll
        for (int c = 0; c < 8; ++c) { qv[c] = (float)q0[c]; qv[8 + c] = (float)q1[c]; }
    }

    // rel score: groups 0..3 use rel_h (index i), 4..7 use rel_w (index j)
    const bool useH = (g < 4);
    const float* rp = useH ? (rel_h + c0 * KW_) : (rel_w + (c0 - 64) * KW_);
    float rel[KW_];
    #pragma unroll
    for (int t = 0; t < KW_; ++t) {
        float r = 0.f;
        #pragma unroll
        for (int c = 0; c < CPG_; ++c) r += qv[c] * rp[c * KW_ + t];
        rel[t] = r;
    }

    // scores: all 49 positions (OOB k == 0 -> score = rel, matches zero-pad)
    float s[KW_ * KW_];
    float smax = -1e30f;
    #pragma unroll
    for (int i = 0; i < KW_; ++i) {
        #pragma unroll
        for (int j = 0; j < KW_; ++j) {
            const unsigned short* kp = &kvls[0][((ph + i) * HALO + (pw + j)) * LP];
            const f16x8 k0 = *(const f16x8*)(kp);
            const f16x8 k1 = *(const f16x8*)(kp + 8);
            float sc = useH ? rel[i] : rel[j];
            #pragma unroll
            for (int c = 0; c < 8; ++c)
                sc += qv[c] * (float)k0[c] + qv[8 + c] * (float)k1[c];
            s[i * KW_ + j] = sc;
            smax = fmaxf(smax, sc);
        }
    }

    // softmax
    float denom = 0.f;
    #pragma unroll
    for (int n = 0; n < KW_ * KW_; ++n) {
        s[n] = __expf(s[n] - smax);
        denom += s[n];
    }
    const float rdenom = 1.f / denom;

    // output = attn . V (OOB v == 0 contributes nothing)
    float acc[CPG_];
    #pragma unroll
    for (int c = 0; c < CPG_; ++c) acc[c] = 0.f;
    #pragma unroll
    for (int i = 0; i < KW_; ++i) {
        #pragma unroll
        for (int j = 0; j < KW_; ++j) {
            const float a = s[i * KW_ + j];
            const unsigned short* vp = &kvls[1][((ph + i) * HALO + (pw + j)) * LP];
            const f16x8 v0 = *(const f16x8*)(vp);
            const f16x8 v1 = *(const f16x8*)(vp + 8);
            #pragma unroll
            for (int c = 0; c < 8; ++c) {
                acc[c]     += a * (float)v0[c];
                acc[8 + c] += a * (float)v1[c];
            }
        }
    }

    float* ob = out + ((size_t)b * C_ + c0) * HW_;
    #pragma unroll
    for (int c = 0; c < CPG_; ++c)
        ob[(size_t)c * HW_ + pix] = acc[c] * rdenom;
}

// ---------------------------------------------------------------------------
extern "C" void kernel_launch(void* const* d_in, const int* in_sizes, int n_in,
                              void* d_out, int out_size, void* d_ws, size_t ws_size,
                              hipStream_t stream) {
    const float* x     = (const float*)d_in[0];
    const float* Wq    = (const float*)d_in[1];
    const float* Wk    = (const float*)d_in[2];
    const float* Wv    = (const float*)d_in[3];
    const float* rel_h = (const float*)d_in[4];
    const float* rel_w = (const float*)d_in[5];
    unsigned short* ws   = (unsigned short*)d_ws;
    unsigned short* qkv  = ws;                                   // [3][B][G][4096][16] fp16
    unsigned short* w16  = ws + (size_t)3 * B_ * HW_ * C_;       // [3][128][128] fp16
    float* out = (float*)d_out;

    w16_kernel<<<48, 256, 0, stream>>>(Wq, Wk, Wv, w16);

    dim3 gA(HW_ / 64, B_, 3);
    proj_mfma<<<gA, 256, 0, stream>>>(x, w16, qkv);

    dim3 gB(16, G_, B_);
    attn_kernel<<<gB, 256, 0, stream>>>(qkv, rel_h, rel_w, out);
}

// Round 8
// 41.637 us; speedup vs baseline: 1.1412x; 1.1412x over previous
//
#include <hip/hip_runtime.h>
#include <hip/hip_bf16.h>

#define B_   4
#define C_   128
#define H_   64
#define W_   64
#define HW_  4096
#define KW_  7
#define PAD_ 3
#define G_   8
#define CPG_ 16

#define CPAD 136   // f16 elems per LDS row in proj; row stride 272 B

// attn LDS geometry
#define TS    16          // spatial tile
#define HALO  22          // TS + 6
#define NHP   (HALO*HALO) // 484 halo pixels
#define KLP   24          // K: padded ushorts per pixel (48 B) -> 2-way banks (free)
#define VLP   12          // V-half: 8 ch + pad (24 B) -> 2-way banks (free)

typedef _Float16 f16x8 __attribute__((ext_vector_type(8)));
typedef float    f32x4 __attribute__((ext_vector_type(4)));

static __device__ __forceinline__ unsigned short f2h(float f) {
    _Float16 h = (_Float16)f;
    union { _Float16 h; unsigned short u; } cv; cv.h = h;
    return cv.u;
}

// ---------------------------------------------------------------------------
// Kernel A: fp16-MFMA 1x1 conv projections (round-6 proven version).
// Output: fp16, GROUP-PLANAR qkv16[m][b][g][pix][16]  (pixel stride 32 B).
// grid: (32 p-tiles, B, 3), block 256 (4 waves).
// ---------------------------------------------------------------------------
__global__ __launch_bounds__(256) void proj_mfma(
    const float* __restrict__ x,
    const float* __restrict__ Wq,
    const float* __restrict__ Wk,
    const float* __restrict__ Wv,
    unsigned short* __restrict__ qkv16)
{
    const int ptile = blockIdx.x;
    const int b     = blockIdx.y;
    const int m     = blockIdx.z;
    const float* Wm = (m == 0) ? Wq : ((m == 1) ? Wk : Wv);
    const float* xb = x + (size_t)b * C_ * HW_;
    unsigned short* y = qkv16 + ((size_t)(m * B_ + b)) * HW_ * C_;
    const int p0  = ptile * 128;
    const int tid = threadIdx.x;

    __shared__ unsigned short wls[128 * CPAD];  // [o][c] f16
    __shared__ unsigned short xls[128 * CPAD];  // [p][c] f16 (transposed X)

    // stage W: 128 o x 128 c
    #pragma unroll
    for (int it = 0; it < 16; ++it) {
        const int idx = tid + it * 256;
        const int o   = idx >> 5;
        const int c4  = (idx & 31) * 4;
        const float4 w4 = *(const float4*)(Wm + (size_t)o * C_ + c4);
        ushort4 hh;
        hh.x = f2h(w4.x); hh.y = f2h(w4.y); hh.z = f2h(w4.z); hh.w = f2h(w4.w);
        *(ushort4*)(&wls[o * CPAD + c4]) = hh;
    }
    // stage X^T: 4c x 4p micro-transpose blocks
    #pragma unroll
    for (int it = 0; it < 4; ++it) {
        const int idx = tid + it * 256;
        const int cq  = (idx >> 5) * 4;
        const int pq  = (idx & 31) * 4;
        const float* xp = xb + (size_t)cq * HW_ + p0 + pq;
        const float4 r0 = *(const float4*)(xp);
        const float4 r1 = *(const float4*)(xp + HW_);
        const float4 r2 = *(const float4*)(xp + 2 * HW_);
        const float4 r3 = *(const float4*)(xp + 3 * HW_);
        ushort4 hh;
        hh.x = f2h(r0.x); hh.y = f2h(r1.x); hh.z = f2h(r2.x); hh.w = f2h(r3.x);
        *(ushort4*)(&xls[(pq + 0) * CPAD + cq]) = hh;
        hh.x = f2h(r0.y); hh.y = f2h(r1.y); hh.z = f2h(r2.y); hh.w = f2h(r3.y);
        *(ushort4*)(&xls[(pq + 1) * CPAD + cq]) = hh;
        hh.x = f2h(r0.z); hh.y = f2h(r1.z); hh.z = f2h(r2.z); hh.w = f2h(r3.z);
        *(ushort4*)(&xls[(pq + 2) * CPAD + cq]) = hh;
        hh.x = f2h(r0.w); hh.y = f2h(r1.w); hh.z = f2h(r2.w); hh.w = f2h(r3.w);
        *(ushort4*)(&xls[(pq + 3) * CPAD + cq]) = hh;
    }
    __syncthreads();

    const int wv   = tid >> 6;     // wave id: owns 32 pixels
    const int lane = tid & 63;
    const int row  = lane & 15;
    const int kq   = lane >> 4;    // k-quad

    f32x4 acc[2][8];
    #pragma unroll
    for (int pt = 0; pt < 2; ++pt)
        #pragma unroll
        for (int ot = 0; ot < 8; ++ot)
            acc[pt][ot] = (f32x4){0.f, 0.f, 0.f, 0.f};

    #pragma unroll
    for (int ks = 0; ks < 4; ++ks) {
        const int cb = ks * 32 + kq * 8;
        // B-operand: pixels (free idx -> lane&15)
        const f16x8 b0 = *(const f16x8*)(&xls[(wv * 32 +      row) * CPAD + cb]);
        const f16x8 b1 = *(const f16x8*)(&xls[(wv * 32 + 16 + row) * CPAD + cb]);
        #pragma unroll
        for (int ot = 0; ot < 8; ++ot) {
            // A-operand: output channels (free idx -> reg axis)
            const f16x8 af = *(const f16x8*)(&wls[(ot * 16 + row) * CPAD + cb]);
            acc[0][ot] = __builtin_amdgcn_mfma_f32_16x16x32_f16(af, b0, acc[0][ot], 0, 0, 0);
            acc[1][ot] = __builtin_amdgcn_mfma_f32_16x16x32_f16(af, b1, acc[1][ot], 0, 0, 0);
        }
    }

    // D: lane holds D[o = ot*16 + kq*4 + reg][p = pt*16 + row (+pbase)]
    // group g == ot; within-group channel = kq*4 + reg.
    const int pbase = p0 + wv * 32;
    #pragma unroll
    for (int pt = 0; pt < 2; ++pt) {
        const int p = pbase + pt * 16 + row;
        #pragma unroll
        for (int ot = 0; ot < 8; ++ot) {
            ushort4 hh;
            hh.x = f2h(acc[pt][ot][0]); hh.y = f2h(acc[pt][ot][1]);
            hh.z = f2h(acc[pt][ot][2]); hh.w = f2h(acc[pt][ot][3]);
            *(ushort4*)(y + ((size_t)ot * HW_ + p) * CPG_ + kq * 4) = hh;
        }
    }
}

// ---------------------------------------------------------------------------
// Kernel B: grouped 7x7 local attention, channel-split for occupancy.
// Each block: one 16x16 tile, one group, ONE HALF of the V/output channels.
// Full K halo staged (full 16-ch score + softmax, duplicated across the two
// halves), half V halo staged, 8-channel PV + store.
// grid: (16 tiles, G*2, B), block 256. LDS 34.8 KB -> 4 blocks/CU.
// ---------------------------------------------------------------------------
__global__ __launch_bounds__(256) void attn_kernel(
    const unsigned short* __restrict__ qkv16,
    const float* __restrict__ rel_h,   // [64][7]
    const float* __restrict__ rel_w,   // [64][7]
    float* __restrict__ out)           // [B][128][64][64]
{
    const int tile = blockIdx.x;
    const int gh   = blockIdx.y;       // 0..15
    const int g    = gh >> 1;
    const int half = gh & 1;
    const int b    = blockIdx.z;
    const int h0   = (tile >> 2) * TS;
    const int w0   = (tile & 3) * TS;
    const int c0   = g * CPG_;

    __shared__ unsigned short kls[NHP * KLP];   // full K halo (16 ch + pad)
    __shared__ unsigned short vls[NHP * VLP];   // half V halo (8 ch + pad)

    const size_t gplane = (size_t)HW_ * CPG_;                 // per (b,g) plane
    const size_t mplane = (size_t)B_ * G_ * gplane;           // per matrix
    const unsigned short* qb = qkv16              + ((size_t)b * G_ + g) * gplane;
    const unsigned short* kb = qkv16 + mplane     + ((size_t)b * G_ + g) * gplane;
    const unsigned short* vb = qkv16 + 2 * mplane + ((size_t)b * G_ + g) * gplane;

    const int tid = threadIdx.x;

    // stage: K full halo = 968 x 16B chunks; V half halo = 484 x 16B chunks
    #pragma unroll
    for (int it = 0; it < 6; ++it) {
        const int idx = tid + it * 256;
        if (idx < NHP * 2) {
            // K chunk
            const int lp = idx >> 1;
            const int hf = idx & 1;
            const int hy = h0 + lp / HALO - PAD_;
            const int hx = w0 + lp % HALO - PAD_;
            f16x8 val = (f16x8)(_Float16)0.f;
            if ((unsigned)hy < (unsigned)H_ && (unsigned)hx < (unsigned)W_)
                val = *(const f16x8*)(kb + (size_t)(hy * W_ + hx) * CPG_ + hf * 8);
            *(f16x8*)(&kls[lp * KLP + hf * 8]) = val;
        } else if (idx < NHP * 2 + NHP) {
            // V half chunk
            const int lp = idx - NHP * 2;
            const int hy = h0 + lp / HALO - PAD_;
            const int hx = w0 + lp % HALO - PAD_;
            f16x8 val = (f16x8)(_Float16)0.f;
            if ((unsigned)hy < (unsigned)H_ && (unsigned)hx < (unsigned)W_)
                val = *(const f16x8*)(vb + (size_t)(hy * W_ + hx) * CPG_ + half * 8);
            *(f16x8*)(&vls[lp * VLP]) = val;
        }
    }
    __syncthreads();

    const int pw  = tid & 15;
    const int ph  = tid >> 4;
    const int pix = (h0 + ph) * W_ + (w0 + pw);

    // q fragment -> fp32 (full 16 ch: score needs the whole dot)
    float qv[CPG_];
    {
        const f16x8 q0 = *(const f16x8*)(qb + (size_t)pix * CPG_);
        const f16x8 q1 = *(const f16x8*)(qb + (size_t)pix * CPG_ + 8);
        #pragma unroll
        for (int c = 0; c < 8; ++c) { qv[c] = (float)q0[c]; qv[8 + c] = (float)q1[c]; }
    }

    // rel score: groups 0..3 use rel_h (index i), 4..7 use rel_w (index j)
    const bool useH = (g < 4);
    const float* rp = useH ? (rel_h + c0 * KW_) : (rel_w + (c0 - 64) * KW_);
    float rel[KW_];
    #pragma unroll
    for (int t = 0; t < KW_; ++t) {
        float r = 0.f;
        #pragma unroll
        for (int c = 0; c < CPG_; ++c) r += qv[c] * rp[c * KW_ + t];
        rel[t] = r;
    }

    // scores: all 49 positions (OOB k == 0 -> score = rel, matches zero-pad)
    float s[KW_ * KW_];
    float smax = -1e30f;
    #pragma unroll
    for (int i = 0; i < KW_; ++i) {
        #pragma unroll
        for (int j = 0; j < KW_; ++j) {
            const unsigned short* kp = &kls[((ph + i) * HALO + (pw + j)) * KLP];
            const f16x8 k0 = *(const f16x8*)(kp);
            const f16x8 k1 = *(const f16x8*)(kp + 8);
            float sc = useH ? rel[i] : rel[j];
            #pragma unroll
            for (int c = 0; c < 8; ++c)
                sc += qv[c] * (float)k0[c] + qv[8 + c] * (float)k1[c];
            s[i * KW_ + j] = sc;
            smax = fmaxf(smax, sc);
        }
    }

    // softmax (identical in both half-blocks)
    float denom = 0.f;
    #pragma unroll
    for (int n = 0; n < KW_ * KW_; ++n) {
        s[n] = __expf(s[n] - smax);
        denom += s[n];
    }
    const float rdenom = 1.f / denom;

    // output = attn . V (this block's 8 channels only)
    float acc[8];
    #pragma unroll
    for (int c = 0; c < 8; ++c) acc[c] = 0.f;
    #pragma unroll
    for (int i = 0; i < KW_; ++i) {
        #pragma unroll
        for (int j = 0; j < KW_; ++j) {
            const float a = s[i * KW_ + j];
            const f16x8 v0 = *(const f16x8*)(&vls[((ph + i) * HALO + (pw + j)) * VLP]);
            #pragma unroll
            for (int c = 0; c < 8; ++c)
                acc[c] += a * (float)v0[c];
        }
    }

    float* ob = out + ((size_t)b * C_ + c0 + half * 8) * HW_;
    #pragma unroll
    for (int c = 0; c < 8; ++c)
        ob[(size_t)c * HW_ + pix] = acc[c] * rdenom;
}

// ---------------------------------------------------------------------------
extern "C" void kernel_launch(void* const* d_in, const int* in_sizes, int n_in,
                              void* d_out, int out_size, void* d_ws, size_t ws_size,
                              hipStream_t stream) {
    const float* x     = (const float*)d_in[0];
    const float* Wq    = (const float*)d_in[1];
    const float* Wk    = (const float*)d_in[2];
    const float* Wv    = (const float*)d_in[3];
    const float* rel_h = (const float*)d_in[4];
    const float* rel_w = (const float*)d_in[5];
    unsigned short* ws = (unsigned short*)d_ws;  // fp16 qkv [3][B][G][4096][16] = 12 MB
    float* out = (float*)d_out;

    dim3 gA(HW_ / 128, B_, 3);
    proj_mfma<<<gA, 256, 0, stream>>>(x, Wq, Wk, Wv, ws);

    dim3 gB(16, G_ * 2, B_);
    attn_kernel<<<gB, 256, 0, stream>>>(ws, rel_h, rel_w, out);
}

// Round 9
// 40.439 us; speedup vs baseline: 1.1750x; 1.0296x over previous
//
#include <hip/hip_runtime.h>
#include <hip/hip_bf16.h>

#define B_   4
#define C_   128
#define H_   64
#define W_   64
#define HW_  4096
#define KW_  7
#define PAD_ 3
#define G_   8
#define CPG_ 16

#define CPAD 136   // f16 elems per LDS row in proj; row stride 272 B (17*16B)
#define WCH  34    // global_load_lds chunks for W image: 128*136*2B / 1024B

// attn LDS geometry (round-6 proven)
#define TS    16          // spatial tile
#define HALO  22          // TS + 6
#define NHP   (HALO*HALO) // 484 halo pixels
#define LP    24          // padded ushorts per pixel (48 B, 16B-aligned)

typedef _Float16 f16x8 __attribute__((ext_vector_type(8)));
typedef float    f32x4 __attribute__((ext_vector_type(4)));

static __device__ __forceinline__ unsigned short f2h(float f) {
    _Float16 h = (_Float16)f;
    union { _Float16 h; unsigned short u; } cv; cv.h = h;
    return cv.u;
}

// ---------------------------------------------------------------------------
// Kernel 0: convert Wq/Wk/Wv (f32) -> fp16 PADDED LDS image w16p[3][128][136]
// (pad halves uninitialized garbage; never read). 12288 quads; grid 48 x 256.
// ---------------------------------------------------------------------------
__global__ __launch_bounds__(256) void w16p_kernel(
    const float* __restrict__ Wq,
    const float* __restrict__ Wk,
    const float* __restrict__ Wv,
    unsigned short* __restrict__ w16p)
{
    const int gid = blockIdx.x * 256 + threadIdx.x;   // quad index
    const int m   = gid >> 12;                        // 4096 quads per matrix
    const int r   = gid & 4095;
    const int o   = r >> 5;                           // row
    const int c4  = (r & 31) * 4;
    const float* src = (m == 0) ? Wq : ((m == 1) ? Wk : Wv);
    const float4 v = *(const float4*)(src + (size_t)o * C_ + c4);
    ushort4 hh;
    hh.x = f2h(v.x); hh.y = f2h(v.y); hh.z = f2h(v.z); hh.w = f2h(v.w);
    *(ushort4*)(w16p + (size_t)m * 128 * CPAD + (size_t)o * CPAD + c4) = hh;
}

// ---------------------------------------------------------------------------
// Kernel A: fp16-MFMA 1x1 conv projections.
// W staged via linear global_load_lds from the pre-padded w16p image
// (no cvt, no VGPR round-trip). X tile = 64 px. LDS 51 KB -> 3 blocks/CU,
// grid 768 = 3.0 blocks/CU.
// Output: fp16, GROUP-PLANAR qkv16[m][b][g][pix][16] (pixel stride 32 B).
// grid: (64 p-tiles, B, 3), block 256 (4 waves).
// ---------------------------------------------------------------------------
__global__ __launch_bounds__(256) void proj_mfma(
    const float* __restrict__ x,
    const unsigned short* __restrict__ w16p,
    unsigned short* __restrict__ qkv16)
{
    const int ptile = blockIdx.x;   // 0..63
    const int b     = blockIdx.y;
    const int m     = blockIdx.z;
    const float* xb = x + (size_t)b * C_ * HW_;
    unsigned short* y = qkv16 + ((size_t)(m * B_ + b)) * HW_ * C_;
    const int p0  = ptile * 64;
    const int tid = threadIdx.x;
    const int wv   = tid >> 6;
    const int lane = tid & 63;

    __shared__ unsigned short wls[128 * CPAD];  // [o][c] f16 (padded image)
    __shared__ unsigned short xls[64 * CPAD];   // [p][c] f16 (transposed X)

    // ---- stage W: 34 x 1024B linear chunks via global_load_lds width=16 ----
    {
        const unsigned short* gsrc = w16p + (size_t)m * 128 * CPAD + lane * 8;
        #pragma unroll
        for (int t = 0; t < 9; ++t) {
            const int idx = wv + 4 * t;     // wave-uniform
            if (idx < WCH) {
                __builtin_amdgcn_global_load_lds(
                    (const __attribute__((address_space(1))) void*)(gsrc + idx * 512),
                    (__attribute__((address_space(3))) void*)(&wls[idx * 512]),
                    16, 0, 0);
            }
        }
    }

    // ---- stage X^T: 4c x 4p micro-transpose blocks (2 iters) ----
    #pragma unroll
    for (int it = 0; it < 2; ++it) {
        const int idx = tid + it * 256;
        const int pq  = (idx & 15) * 4;
        const int cq  = (idx >> 4) * 4;
        const float* xp = xb + (size_t)cq * HW_ + p0 + pq;
        const float4 r0 = *(const float4*)(xp);
        const float4 r1 = *(const float4*)(xp + HW_);
        const float4 r2 = *(const float4*)(xp + 2 * HW_);
        const float4 r3 = *(const float4*)(xp + 3 * HW_);
        ushort4 hh;
        hh.x = f2h(r0.x); hh.y = f2h(r1.x); hh.z = f2h(r2.x); hh.w = f2h(r3.x);
        *(ushort4*)(&xls[(pq + 0) * CPAD + cq]) = hh;
        hh.x = f2h(r0.y); hh.y = f2h(r1.y); hh.z = f2h(r2.y); hh.w = f2h(r3.y);
        *(ushort4*)(&xls[(pq + 1) * CPAD + cq]) = hh;
        hh.x = f2h(r0.z); hh.y = f2h(r1.z); hh.z = f2h(r2.z); hh.w = f2h(r3.z);
        *(ushort4*)(&xls[(pq + 2) * CPAD + cq]) = hh;
        hh.x = f2h(r0.w); hh.y = f2h(r1.w); hh.z = f2h(r2.w); hh.w = f2h(r3.w);
        *(ushort4*)(&xls[(pq + 3) * CPAD + cq]) = hh;
    }
    __syncthreads();   // drains vmcnt (global_load_lds) + lgkm before reads

    const int row  = lane & 15;
    const int kq   = lane >> 4;    // k-quad

    f32x4 acc[8];
    #pragma unroll
    for (int ot = 0; ot < 8; ++ot)
        acc[ot] = (f32x4){0.f, 0.f, 0.f, 0.f};

    #pragma unroll
    for (int ks = 0; ks < 4; ++ks) {
        const int cb = ks * 32 + kq * 8;
        // B-operand: pixels (free idx -> lane&15); wave owns 16 px
        const f16x8 bfrag = *(const f16x8*)(&xls[(wv * 16 + row) * CPAD + cb]);
        #pragma unroll
        for (int ot = 0; ot < 8; ++ot) {
            // A-operand: output channels (free idx -> reg axis)
            const f16x8 afrag = *(const f16x8*)(&wls[(ot * 16 + row) * CPAD + cb]);
            acc[ot] = __builtin_amdgcn_mfma_f32_16x16x32_f16(afrag, bfrag, acc[ot], 0, 0, 0);
        }
    }

    // D: lane holds D[o = ot*16 + kq*4 + reg][p = p0 + wv*16 + row]
    // group g == ot; within-group channel = kq*4 + reg.
    const int p = p0 + wv * 16 + row;
    #pragma unroll
    for (int ot = 0; ot < 8; ++ot) {
        ushort4 hh;
        hh.x = f2h(acc[ot][0]); hh.y = f2h(acc[ot][1]);
        hh.z = f2h(acc[ot][2]); hh.w = f2h(acc[ot][3]);
        *(ushort4*)(y + ((size_t)ot * HW_ + p) * CPG_ + kq * 4) = hh;
    }
}

// ---------------------------------------------------------------------------
// Kernel B: grouped 7x7 local attention, fp16 K/V halo staged in LDS.
// VERBATIM round-6 version (best-known, replay-proven).
// grid: (16 tiles, G, B), block 256 = one 16x16 tile, one group.
// ---------------------------------------------------------------------------
__global__ __launch_bounds__(256) void attn_kernel(
    const unsigned short* __restrict__ qkv16,
    const float* __restrict__ rel_h,   // [64][7]
    const float* __restrict__ rel_w,   // [64][7]
    float* __restrict__ out)           // [B][128][64][64]
{
    const int tile = blockIdx.x;
    const int g    = blockIdx.y;
    const int b    = blockIdx.z;
    const int h0   = (tile >> 2) * TS;
    const int w0   = (tile & 3) * TS;
    const int c0   = g * CPG_;

    __shared__ unsigned short kvls[2][NHP * LP];   // [k/v][pixel*24]

    const size_t gplane = (size_t)HW_ * CPG_;                 // per (b,g) plane
    const size_t mplane = (size_t)B_ * G_ * gplane;           // per matrix
    const unsigned short* qb = qkv16              + ((size_t)b * G_ + g) * gplane;
    const unsigned short* kb = qkv16 + mplane     + ((size_t)b * G_ + g) * gplane;
    const unsigned short* vb = qkv16 + 2 * mplane + ((size_t)b * G_ + g) * gplane;

    const int tid = threadIdx.x;

    // stage K and V halo: 1936 x 16B chunks, coalesced, zero-fill OOB
    #pragma unroll
    for (int it = 0; it < 8; ++it) {
        const int idx = tid + it * 256;
        if (idx < 2 * NHP * 2) {
            const int arr  = (idx >= NHP * 2) ? 1 : 0;
            const int r    = idx - arr * NHP * 2;
            const int lp   = r >> 1;
            const int half = r & 1;
            const int hy   = h0 + lp / HALO - PAD_;
            const int hx   = w0 + lp % HALO - PAD_;
            f16x8 val = (f16x8)(_Float16)0.f;
            if ((unsigned)hy < (unsigned)H_ && (unsigned)hx < (unsigned)W_) {
                const unsigned short* src = (arr ? vb : kb)
                    + (size_t)(hy * W_ + hx) * CPG_ + half * 8;
                val = *(const f16x8*)src;
            }
            *(f16x8*)(&kvls[arr][lp * LP + half * 8]) = val;
        }
    }
    __syncthreads();

    const int pw  = tid & 15;
    const int ph  = tid >> 4;
    const int pix = (h0 + ph) * W_ + (w0 + pw);

    // q fragment -> fp32
    float qv[CPG_];
    {
        const f16x8 q0 = *(const f16x8*)(qb + (size_t)pix * CPG_);
        const f16x8 q1 = *(const f16x8*)(qb + (size_t)pix * CPG_ + 8);
        #pragma unroll
        for (int c = 0; c < 8; ++c) { qv[c] = (float)q0[c]; qv[8 + c] = (float)q1[c]; }
    }

    // rel score: groups 0..3 use rel_h (index i), 4..7 use rel_w (index j)
    const bool useH = (g < 4);
    const float* rp = useH ? (rel_h + c0 * KW_) : (rel_w + (c0 - 64) * KW_);
    float rel[KW_];
    #pragma unroll
    for (int t = 0; t < KW_; ++t) {
        float r = 0.f;
        #pragma unroll
        for (int c = 0; c < CPG_; ++c) r += qv[c] * rp[c * KW_ + t];
        rel[t] = r;
    }

    // scores: all 49 positions (OOB k == 0 -> score = rel, matches zero-pad)
    float s[KW_ * KW_];
    float smax = -1e30f;
    #pragma unroll
    for (int i = 0; i < KW_; ++i) {
        #pragma unroll
        for (int j = 0; j < KW_; ++j) {
            const unsigned short* kp = &kvls[0][((ph + i) * HALO + (pw + j)) * LP];
            const f16x8 k0 = *(const f16x8*)(kp);
            const f16x8 k1 = *(const f16x8*)(kp + 8);
            float sc = useH ? rel[i] : rel[j];
            #pragma unroll
            for (int c = 0; c < 8; ++c)
                sc += qv[c] * (float)k0[c] + qv[8 + c] * (float)k1[c];
            s[i * KW_ + j] = sc;
            smax = fmaxf(smax, sc);
        }
    }

    // softmax
    float denom = 0.f;
    #pragma unroll
    for (int n = 0; n < KW_ * KW_; ++n) {
        s[n] = __expf(s[n] - smax);
        denom += s[n];
    }
    const float rdenom = 1.f / denom;

    // output = attn . V (OOB v == 0 contributes nothing)
    float acc[CPG_];
    #pragma unroll
    for (int c = 0; c < CPG_; ++c) acc[c] = 0.f;
    #pragma unroll
    for (int i = 0; i < KW_; ++i) {
        #pragma unroll
        for (int j = 0; j < KW_; ++j) {
            const float a = s[i * KW_ + j];
            const unsigned short* vp = &kvls[1][((ph + i) * HALO + (pw + j)) * LP];
            const f16x8 v0 = *(const f16x8*)(vp);
            const f16x8 v1 = *(const f16x8*)(vp + 8);
            #pragma unroll
            for (int c = 0; c < 8; ++c) {
                acc[c]     += a * (float)v0[c];
                acc[8 + c] += a * (float)v1[c];
            }
        }
    }

    float* ob = out + ((size_t)b * C_ + c0) * HW_;
    #pragma unroll
    for (int c = 0; c < CPG_; ++c)
        ob[(size_t)c * HW_ + pix] = acc[c] * rdenom;
}

// ---------------------------------------------------------------------------
extern "C" void kernel_launch(void* const* d_in, const int* in_sizes, int n_in,
                              void* d_out, int out_size, void* d_ws, size_t ws_size,
                              hipStream_t stream) {
    const float* x     = (const float*)d_in[0];
    const float* Wq    = (const float*)d_in[1];
    const float* Wk    = (const float*)d_in[2];
    const float* Wv    = (const float*)d_in[3];
    const float* rel_h = (const float*)d_in[4];
    const float* rel_w = (const float*)d_in[5];
    unsigned short* ws   = (unsigned short*)d_ws;
    unsigned short* qkv  = ws;                                   // [3][B][G][4096][16] fp16 (12 MB)
    unsigned short* w16p = ws + (size_t)3 * B_ * HW_ * C_;       // [3][128][136] fp16 padded image
    float* out = (float*)d_out;

    w16p_kernel<<<48, 256, 0, stream>>>(Wq, Wk, Wv, w16p);

    dim3 gA(HW_ / 64, B_, 3);
    proj_mfma<<<gA, 256, 0, stream>>>(x, w16p, qkv);

    dim3 gB(16, G_, B_);
    attn_kernel<<<gB, 256, 0, stream>>>(qkv, rel_h, rel_w, out);
}

// Round 10
// 33.158 us; speedup vs baseline: 1.4330x; 1.2196x over previous
//
#include <hip/hip_runtime.h>
#include <hip/hip_bf16.h>

#define B_   4
#define C_   128
#define H_   64
#define W_   64
#define HW_  4096
#define KW_  7
#define PAD_ 3
#define G_   8
#define CPG_ 16

#define CPAD 136   // f16 elems per LDS row in proj; row stride 272 B

// attn LDS geometry (round-6 proven)
#define TS    16
#define HALO  22
#define NHP   (HALO*HALO)
#define LP    24

typedef _Float16 f16x8 __attribute__((ext_vector_type(8)));
typedef _Float16 h2    __attribute__((ext_vector_type(2)));
typedef float    f32x4 __attribute__((ext_vector_type(4)));

static __device__ __forceinline__ unsigned short f2h(float f) {
    _Float16 h = (_Float16)f;
    union { _Float16 h; unsigned short u; } cv; cv.h = h;
    return cv.u;
}

#if defined(__has_builtin)
#if __has_builtin(__builtin_amdgcn_fdot2)
#define HAVE_FDOT2 1
#endif
#endif

// ---------------------------------------------------------------------------
// Kernel A: fp16-MFMA 1x1 conv projections. 64-px X tile, in-block W cvt.
// LDS 52.2 KB -> 3 blocks/CU; grid 768 = 3.0/CU balanced.
// Output: fp16, GROUP-PLANAR qkv16[m][b][g][pix][16] (pixel stride 32 B).
// grid: (64 p-tiles, B, 3), block 256 (4 waves).
// ---------------------------------------------------------------------------
__global__ __launch_bounds__(256) void proj_mfma(
    const float* __restrict__ x,
    const float* __restrict__ Wq,
    const float* __restrict__ Wk,
    const float* __restrict__ Wv,
    unsigned short* __restrict__ qkv16)
{
    const int ptile = blockIdx.x;   // 0..63
    const int b     = blockIdx.y;
    const int m     = blockIdx.z;
    const float* Wm = (m == 0) ? Wq : ((m == 1) ? Wk : Wv);
    const float* xb = x + (size_t)b * C_ * HW_;
    unsigned short* y = qkv16 + ((size_t)(m * B_ + b)) * HW_ * C_;
    const int p0  = ptile * 64;
    const int tid = threadIdx.x;

    __shared__ unsigned short wls[128 * CPAD];  // [o][c] f16
    __shared__ unsigned short xls[64 * CPAD];   // [p][c] f16 (transposed X)

    // stage W: 128 o x 128 c (cvt in-block; no extra dispatch)
    #pragma unroll
    for (int it = 0; it < 16; ++it) {
        const int idx = tid + it * 256;
        const int o   = idx >> 5;
        const int c4  = (idx & 31) * 4;
        const float4 w4 = *(const float4*)(Wm + (size_t)o * C_ + c4);
        ushort4 hh;
        hh.x = f2h(w4.x); hh.y = f2h(w4.y); hh.z = f2h(w4.z); hh.w = f2h(w4.w);
        *(ushort4*)(&wls[o * CPAD + c4]) = hh;
    }
    // stage X^T: 4c x 4p micro-transpose blocks (2 iters)
    #pragma unroll
    for (int it = 0; it < 2; ++it) {
        const int idx = tid + it * 256;
        const int pq  = (idx & 15) * 4;
        const int cq  = (idx >> 4) * 4;
        const float* xp = xb + (size_t)cq * HW_ + p0 + pq;
        const float4 r0 = *(const float4*)(xp);
        const float4 r1 = *(const float4*)(xp + HW_);
        const float4 r2 = *(const float4*)(xp + 2 * HW_);
        const float4 r3 = *(const float4*)(xp + 3 * HW_);
        ushort4 hh;
        hh.x = f2h(r0.x); hh.y = f2h(r1.x); hh.z = f2h(r2.x); hh.w = f2h(r3.x);
        *(ushort4*)(&xls[(pq + 0) * CPAD + cq]) = hh;
        hh.x = f2h(r0.y); hh.y = f2h(r1.y); hh.z = f2h(r2.y); hh.w = f2h(r3.y);
        *(ushort4*)(&xls[(pq + 1) * CPAD + cq]) = hh;
        hh.x = f2h(r0.z); hh.y = f2h(r1.z); hh.z = f2h(r2.z); hh.w = f2h(r3.z);
        *(ushort4*)(&xls[(pq + 2) * CPAD + cq]) = hh;
        hh.x = f2h(r0.w); hh.y = f2h(r1.w); hh.z = f2h(r2.w); hh.w = f2h(r3.w);
        *(ushort4*)(&xls[(pq + 3) * CPAD + cq]) = hh;
    }
    __syncthreads();

    const int wv   = tid >> 6;     // wave id: owns 16 pixels
    const int lane = tid & 63;
    const int row  = lane & 15;
    const int kq   = lane >> 4;

    f32x4 acc[8];
    #pragma unroll
    for (int ot = 0; ot < 8; ++ot)
        acc[ot] = (f32x4){0.f, 0.f, 0.f, 0.f};

    #pragma unroll
    for (int ks = 0; ks < 4; ++ks) {
        const int cb = ks * 32 + kq * 8;
        const f16x8 bfrag = *(const f16x8*)(&xls[(wv * 16 + row) * CPAD + cb]);
        #pragma unroll
        for (int ot = 0; ot < 8; ++ot) {
            const f16x8 afrag = *(const f16x8*)(&wls[(ot * 16 + row) * CPAD + cb]);
            acc[ot] = __builtin_amdgcn_mfma_f32_16x16x32_f16(afrag, bfrag, acc[ot], 0, 0, 0);
        }
    }

    // D: lane holds D[o = ot*16 + kq*4 + reg][p = p0 + wv*16 + row]
    const int p = p0 + wv * 16 + row;
    #pragma unroll
    for (int ot = 0; ot < 8; ++ot) {
        ushort4 hh;
        hh.x = f2h(acc[ot][0]); hh.y = f2h(acc[ot][1]);
        hh.z = f2h(acc[ot][2]); hh.w = f2h(acc[ot][3]);
        *(ushort4*)(y + ((size_t)ot * HW_ + p) * CPG_ + kq * 4) = hh;
    }
}

// ---------------------------------------------------------------------------
// Kernel B: grouped 7x7 local attention (round-6 structure), score dot via
// v_dot2_f32_f16 when available.
// grid: (16 tiles, G, B), block 256.
// ---------------------------------------------------------------------------
__global__ __launch_bounds__(256) void attn_kernel(
    const unsigned short* __restrict__ qkv16,
    const float* __restrict__ rel_h,   // [64][7]
    const float* __restrict__ rel_w,   // [64][7]
    float* __restrict__ out)           // [B][128][64][64]
{
    const int tile = blockIdx.x;
    const int g    = blockIdx.y;
    const int b    = blockIdx.z;
    const int h0   = (tile >> 2) * TS;
    const int w0   = (tile & 3) * TS;
    const int c0   = g * CPG_;

    __shared__ unsigned short kvls[2][NHP * LP];

    const size_t gplane = (size_t)HW_ * CPG_;
    const size_t mplane = (size_t)B_ * G_ * gplane;
    const unsigned short* qb = qkv16              + ((size_t)b * G_ + g) * gplane;
    const unsigned short* kb = qkv16 + mplane     + ((size_t)b * G_ + g) * gplane;
    const unsigned short* vb = qkv16 + 2 * mplane + ((size_t)b * G_ + g) * gplane;

    const int tid = threadIdx.x;
    const int pw  = tid & 15;
    const int ph  = tid >> 4;
    const int pix = (h0 + ph) * W_ + (w0 + pw);

    // q fragment first (independent of staging -> overlaps)
    const f16x8 q0 = *(const f16x8*)(qb + (size_t)pix * CPG_);
    const f16x8 q1 = *(const f16x8*)(qb + (size_t)pix * CPG_ + 8);

    // stage K and V halo: 1936 x 16B chunks, coalesced, zero-fill OOB
    #pragma unroll
    for (int it = 0; it < 8; ++it) {
        const int idx = tid + it * 256;
        if (idx < 2 * NHP * 2) {
            const int arr  = (idx >= NHP * 2) ? 1 : 0;
            const int r    = idx - arr * NHP * 2;
            const int lp   = r >> 1;
            const int half = r & 1;
            const int hy   = h0 + lp / HALO - PAD_;
            const int hx   = w0 + lp % HALO - PAD_;
            f16x8 val = (f16x8)(_Float16)0.f;
            if ((unsigned)hy < (unsigned)H_ && (unsigned)hx < (unsigned)W_) {
                const unsigned short* src = (arr ? vb : kb)
                    + (size_t)(hy * W_ + hx) * CPG_ + half * 8;
                val = *(const f16x8*)src;
            }
            *(f16x8*)(&kvls[arr][lp * LP + half * 8]) = val;
        }
    }

    float qv[CPG_];
    #pragma unroll
    for (int c = 0; c < 8; ++c) { qv[c] = (float)q0[c]; qv[8 + c] = (float)q1[c]; }

    // rel score
    const bool useH = (g < 4);
    const float* rp = useH ? (rel_h + c0 * KW_) : (rel_w + (c0 - 64) * KW_);
    float rel[KW_];
    #pragma unroll
    for (int t = 0; t < KW_; ++t) {
        float r = 0.f;
        #pragma unroll
        for (int c = 0; c < CPG_; ++c) r += qv[c] * rp[c * KW_ + t];
        rel[t] = r;
    }

    __syncthreads();

    // scores: all 49 positions
    float s[KW_ * KW_];
    float smax = -1e30f;
    #pragma unroll
    for (int i = 0; i < KW_; ++i) {
        #pragma unroll
        for (int j = 0; j < KW_; ++j) {
            const unsigned short* kp = &kvls[0][((ph + i) * HALO + (pw + j)) * LP];
            const f16x8 k0 = *(const f16x8*)(kp);
            const f16x8 k1 = *(const f16x8*)(kp + 8);
            float sc = useH ? rel[i] : rel[j];
#ifdef HAVE_FDOT2
            #pragma unroll
            for (int t = 0; t < 4; ++t) {
                sc = __builtin_amdgcn_fdot2((h2){q0[2*t], q0[2*t+1]},
                                            (h2){k0[2*t], k0[2*t+1]}, sc, false);
                sc = __builtin_amdgcn_fdot2((h2){q1[2*t], q1[2*t+1]},
                                            (h2){k1[2*t], k1[2*t+1]}, sc, false);
            }
#else
            #pragma unroll
            for (int c = 0; c < 8; ++c)
                sc += qv[c] * (float)k0[c] + qv[8 + c] * (float)k1[c];
#endif
            s[i * KW_ + j] = sc;
            smax = fmaxf(smax, sc);
        }
    }

    // softmax
    float denom = 0.f;
    #pragma unroll
    for (int n = 0; n < KW_ * KW_; ++n) {
        s[n] = __expf(s[n] - smax);
        denom += s[n];
    }
    const float rdenom = 1.f / denom;

    // output = attn . V
    float acc[CPG_];
    #pragma unroll
    for (int c = 0; c < CPG_; ++c) acc[c] = 0.f;
    #pragma unroll
    for (int i = 0; i < KW_; ++i) {
        #pragma unroll
        for (int j = 0; j < KW_; ++j) {
            const float a = s[i * KW_ + j];
            const unsigned short* vp = &kvls[1][((ph + i) * HALO + (pw + j)) * LP];
            const f16x8 v0 = *(const f16x8*)(vp);
            const f16x8 v1 = *(const f16x8*)(vp + 8);
            #pragma unroll
            for (int c = 0; c < 8; ++c) {
                acc[c]     += a * (float)v0[c];
                acc[8 + c] += a * (float)v1[c];
            }
        }
    }

    float* ob = out + ((size_t)b * C_ + c0) * HW_;
    #pragma unroll
    for (int c = 0; c < CPG_; ++c)
        ob[(size_t)c * HW_ + pix] = acc[c] * rdenom;
}

// ---------------------------------------------------------------------------
extern "C" void kernel_launch(void* const* d_in, const int* in_sizes, int n_in,
                              void* d_out, int out_size, void* d_ws, size_t ws_size,
                              hipStream_t stream) {
    const float* x     = (const float*)d_in[0];
    const float* Wq    = (const float*)d_in[1];
    const float* Wk    = (const float*)d_in[2];
    const float* Wv    = (const float*)d_in[3];
    const float* rel_h = (const float*)d_in[4];
    const float* rel_w = (const float*)d_in[5];
    unsigned short* ws = (unsigned short*)d_ws;  // fp16 qkv [3][B][G][4096][16] = 12 MB
    float* out = (float*)d_out;

    dim3 gA(HW_ / 64, B_, 3);
    proj_mfma<<<gA, 256, 0, stream>>>(x, Wq, Wk, Wv, ws);

    dim3 gB(16, G_, B_);
    attn_kernel<<<gB, 256, 0, stream>>>(ws, rel_h, rel_w, out);
}